// Round 3
// baseline (350.015 us; speedup 1.0000x reference)
//
#include <hip/hip_runtime.h>
#include <math.h>

#define BS 4096
#define D 128
#define NC 512
#define NSLICE 16
#define SLICE_COLS 256
#define MARGINF 0.1f
#define NEGV -1e30f

typedef float f32x4 __attribute__((ext_vector_type(4)));
typedef short s16x8 __attribute__((ext_vector_type(8)));

// swizzled LDS byte offset: row stride 256B, 16B chunks XOR'd with row&7 (T2)
__device__ __forceinline__ int swz(int r, int c) {
    return r * 256 + ((c ^ (r & 7)) << 4);
}

__device__ __forceinline__ unsigned short f2bf(float f) {
    unsigned int u = __float_as_uint(f);
    unsigned int r = u + 0x7FFFu + ((u >> 16) & 1u);
    return (unsigned short)(r >> 16);
}

// ordering: higher value first; tie -> lower index (low 16 bits of key).
__device__ __forceinline__ bool better(float v1, int k1, float v2, int k2) {
    if (v1 != v2) return v1 > v2;
    return (k1 & 0xFFFF) < (k2 & 0xFFFF);
}

__device__ __forceinline__ void insert5(float v, int k, float (&V)[5], int (&Kk)[5]) {
    if (!better(v, k, V[4], Kk[4])) return;
    V[4] = v; Kk[4] = k;
#pragma unroll
    for (int t = 4; t > 0; --t) {
        if (better(V[t], Kk[t], V[t - 1], Kk[t - 1])) {
            float tv = V[t]; V[t] = V[t - 1]; V[t - 1] = tv;
            int tk = Kk[t]; Kk[t] = Kk[t - 1]; Kk[t - 1] = tk;
        }
    }
}

// norms (exact f32) + class histogram + bf16 copy of X
__global__ void prep_kernel(const float* __restrict__ X, const int* __restrict__ labels,
                            float* __restrict__ norms, int* __restrict__ counts,
                            unsigned short* __restrict__ Xbf) {
    int t = blockIdx.x * 256 + threadIdx.x;       // float4 index, 131072 total
    int r = t >> 5, kq = t & 31;
    float4 v = ((const float4*)X)[t];
    float acc = v.x * v.x + v.y * v.y + v.z * v.z + v.w * v.w;
#pragma unroll
    for (int off = 1; off < 32; off <<= 1) acc += __shfl_xor(acc, off);
    if (kq == 0) norms[r] = acc;
    ushort4 hv = { f2bf(v.x), f2bf(v.y), f2bf(v.z), f2bf(v.w) };
    ((ushort4*)Xbf)[t] = hv;
    if (t < BS) atomicAdd(&counts[labels[t]], 1);
}

// block: 128 rows x 256 cols (2 panels of 128). 4 waves, each 32 rows x 128 cols.
// LDS: [0,32768) A panel then S spill (wave-local rows); [32768,65536) B panel.
__global__ __launch_bounds__(256) void main_kernel(
        const unsigned short* __restrict__ Xbf, const int* __restrict__ labels,
        const float* __restrict__ norms, float* __restrict__ lists) {
    __shared__ __align__(16) char lds[66560];
    float* ncS = (float*)(lds + 65536);
    int*   lcS = (int*)(lds + 66048);

    const int t = threadIdx.x;
    const int bx = blockIdx.x;
    const int rb = bx >> 4, cs = bx & 15;
    const int row0 = rb * 128;
    const int l = t & 63, w = t >> 6;

    // selection identity: thread owns row rsel (within its own wave's 32 rows)
    const int rsel = t >> 1;          // 0..127, wave-local range [32w, 32w+32)
    const int h = t & 1;
    const int rowG = row0 + rsel;
    const float nR = norms[rowG];
    const int   lR = labels[rowG];

    // ---- stage A panel (swizzled) ----
#pragma unroll
    for (int i = 0; i < 8; ++i) {
        int idx = i * 256 + t;
        int r = idx >> 4, c = idx & 15;
        s16x8 v = *(const s16x8*)(Xbf + (size_t)(row0 + r) * D + c * 8);
        *(s16x8*)(lds + swz(r, c)) = v;
    }
    __syncthreads();

    // ---- hoist A fragments to registers (own-wave rows only) ----
    s16x8 af[2][4];
#pragma unroll
    for (int i = 0; i < 2; ++i)
#pragma unroll
        for (int ks = 0; ks < 4; ++ks) {
            int r = 32 * w + i * 16 + (l & 15);
            int c = ks * 4 + (l >> 4);
            af[i][ks] = *(const s16x8*)(lds + swz(r, c));
        }

    float gV[5]; int gK[5]; float sV[5]; int sK[5];
#pragma unroll
    for (int i = 0; i < 5; ++i) { gV[i] = NEGV; gK[i] = 0xFFFF; sV[i] = NEGV; sK[i] = 0xFFFF; }

    for (int p = 0; p < 2; ++p) {
        const int col0 = cs * SLICE_COLS + p * 128;
        __syncthreads();   // all waves done reading prev B panel

        // ---- stage B panel (swizzled) ----
#pragma unroll
        for (int i = 0; i < 8; ++i) {
            int idx = i * 256 + t;
            int r = idx >> 4, c = idx & 15;
            s16x8 v = *(const s16x8*)(Xbf + (size_t)(col0 + r) * D + c * 8);
            *(s16x8*)(lds + 32768 + swz(r, c)) = v;
        }
        if (t < 128) { ncS[t] = norms[col0 + t]; lcS[t] = labels[col0 + t]; }
        __syncthreads();   // B ready

        // ---- MFMA: 32 rows x 128 cols per wave ----
        f32x4 acc[2][8];
#pragma unroll
        for (int i = 0; i < 2; ++i)
#pragma unroll
            for (int j = 0; j < 8; ++j) acc[i][j] = (f32x4){0.f, 0.f, 0.f, 0.f};

#pragma unroll
        for (int ks = 0; ks < 4; ++ks) {
            s16x8 bf8[8];
#pragma unroll
            for (int j = 0; j < 8; ++j) {
                int r = j * 16 + (l & 15);
                int c = ks * 4 + (l >> 4);
                bf8[j] = *(const s16x8*)(lds + 32768 + swz(r, c));
            }
#pragma unroll
            for (int i = 0; i < 2; ++i)
#pragma unroll
                for (int j = 0; j < 8; ++j)
                    acc[i][j] = __builtin_amdgcn_mfma_f32_16x16x32_bf16(af[i][ks], bf8[j], acc[i][j], 0, 0, 0);
        }

        // ---- two wave-local spill+select rounds (64 cols each), no barriers ----
#pragma unroll
        for (int hf = 0; hf < 2; ++hf) {
            // spill own rows [32w,32w+32), cols hf*64..+64 into A region as f32
#pragma unroll
            for (int i = 0; i < 2; ++i)
#pragma unroll
                for (int jj = 0; jj < 4; ++jj) {
                    int j = hf * 4 + jj;
#pragma unroll
                    for (int e = 0; e < 4; ++e) {
                        int r = 32 * w + i * 16 + (l >> 4) * 4 + e;
                        int c = jj * 16 + (l & 15);          // 0..63
                        *(float*)(lds + swz(r, c >> 2) + (c & 3) * 4) = acc[i][j][e];
                    }
                }
            // select over own row (DS ops are in-order per wave)
#pragma unroll
            for (int i4 = 0; i4 < 8; ++i4) {
                int c4 = h * 8 + i4;                          // 16B chunk 0..15
                f32x4 s4 = *(const f32x4*)(lds + swz(rsel, c4));
#pragma unroll
                for (int e = 0; e < 4; ++e) {
                    int cpan = hf * 64 + c4 * 4 + e;          // panel-local col 0..127
                    int j = col0 + cpan;
                    float d2 = fmaxf(nR + ncS[cpan] - 2.f * s4[e], 0.f);
                    float sim = (j == rowG) ? 0.f : -sqrtf(d2);
                    bool same = (lcS[cpan] == lR);
                    float simi = same ? sim : (sim + MARGINF);
                    insert5(simi, j | (same ? 0x10000 : 0), gV, gK);
                    if (same) insert5(simi, j, sV, sK);
                }
            }
        }
    }

    // ---- merge the two col-half lists (snapshot partner first) ----
    float bv5[5]; int bk5[5];
#pragma unroll
    for (int i = 0; i < 5; ++i) { bv5[i] = __shfl_xor(gV[i], 1); bk5[i] = __shfl_xor(gK[i], 1); }
#pragma unroll
    for (int i = 0; i < 5; ++i) insert5(bv5[i], bk5[i], gV, gK);
#pragma unroll
    for (int i = 0; i < 5; ++i) { bv5[i] = __shfl_xor(sV[i], 1); bk5[i] = __shfl_xor(sK[i], 1); }
#pragma unroll
    for (int i = 0; i < 5; ++i) insert5(bv5[i], bk5[i], sV, sK);

    if (h == 0) {
        float* Lp = lists + (size_t)(rowG * NSLICE + cs) * 20;
        int* Li = (int*)Lp;
#pragma unroll
        for (int i = 0; i < 5; ++i) {
            Lp[i] = gV[i]; Li[5 + i] = gK[i];
            Lp[10 + i] = sV[i]; Li[15 + i] = sK[i];
        }
    }
}

__global__ void merge_kernel(const float* __restrict__ lists, const int* __restrict__ counts,
                             const int* __restrict__ labels, float* __restrict__ rowres) {
    int r = blockIdx.x * 256 + threadIdx.x;
    if (r >= BS) return;
    float gV[5]; int gK[5]; float sV[5]; int sK[5];
#pragma unroll
    for (int i = 0; i < 5; ++i) { gV[i] = NEGV; gK[i] = 0xFFFF; sV[i] = NEGV; sK[i] = 0xFFFF; }
    for (int s2 = 0; s2 < NSLICE; ++s2) {
        const float* Lp = lists + (size_t)(r * NSLICE + s2) * 20;
        const int* Li = (const int*)Lp;
#pragma unroll
        for (int i = 0; i < 5; ++i) insert5(Lp[i], Li[5 + i], gV, gK);
#pragma unroll
        for (int i = 0; i < 5; ++i) insert5(Lp[10 + i], Li[15 + i], sV, sK);
    }
    int pos = counts[labels[r]];
    int ks = (pos < 5) ? pos : 5;
    float fpsum = 0.f; int fpn = 0;
#pragma unroll
    for (int i = 0; i < 5; ++i) {
        bool isFp = (i < ks) && !((gK[i] >> 16) & 1);
        if (isFp) { fpsum += gV[i]; fpn++; }
    }
    int s0 = ks - fpn;
    float fnsum = 0.f;
#pragma unroll
    for (int i = 0; i < 5; ++i)
        if (i >= s0 && i < s0 + fpn) fnsum += sV[i];
    rowres[r] = fpsum - fnsum;
}

__global__ void reduce_kernel(const float* __restrict__ rowres, float* __restrict__ out) {
    __shared__ float sh[256];
    float acc = 0.f;
    for (int i = threadIdx.x; i < BS; i += 256) acc += rowres[i];
    sh[threadIdx.x] = acc;
    __syncthreads();
    for (int s = 128; s > 0; s >>= 1) {
        if (threadIdx.x < s) sh[threadIdx.x] += sh[threadIdx.x + s];
        __syncthreads();
    }
    if (threadIdx.x == 0) out[0] = sh[0];
}

extern "C" void kernel_launch(void* const* d_in, const int* in_sizes, int n_in,
                              void* d_out, int out_size, void* d_ws, size_t ws_size,
                              hipStream_t stream) {
    const float* X      = (const float*)d_in[0];
    const int*   labels = (const int*)d_in[1];

    float* ws     = (float*)d_ws;
    float* norms  = ws;                         // 4096 f32
    float* rowres = ws + BS;                    // 4096 f32
    int*   counts = (int*)(ws + 2 * BS);        // 512 i32
    float* lists  = ws + 2 * BS + NC;           // 4096*16*20 f32 = 5.24 MB
    unsigned short* Xbf = (unsigned short*)(ws + 2 * BS + NC + BS * NSLICE * 20); // 1 MB

    hipMemsetAsync(counts, 0, NC * sizeof(int), stream);
    prep_kernel<<<(BS * D / 4) / 256, 256, 0, stream>>>(X, labels, norms, counts, Xbf);
    main_kernel<<<32 * NSLICE, 256, 0, stream>>>(Xbf, labels, norms, lists);
    merge_kernel<<<BS / 256, 256, 0, stream>>>(lists, counts, labels, rowres);
    reduce_kernel<<<1, 256, 0, stream>>>(rowres, (float*)d_out);
}

// Round 4
// 100.666 us; speedup vs baseline: 3.4770x; 3.4770x over previous
//
#include <hip/hip_runtime.h>
#include <math.h>

#define BS 4096
#define D 128
#define NC 512
#define NSLICE 16
#define SLICE_COLS 256
#define MARGINF 0.1f
#define NEGV -1e30f
#define BIGD 1e30f

typedef float f32x4 __attribute__((ext_vector_type(4)));
typedef short s16x8 __attribute__((ext_vector_type(8)));

__device__ __forceinline__ unsigned short f2bf(float f) {
    unsigned int u = __float_as_uint(f);
    unsigned int r = u + 0x7FFFu + ((u >> 16) & 1u);
    return (unsigned short)(r >> 16);
}

// ---- predicated sorted-insert, ascending by value (best = smallest) ----
// strict <  => equal values keep earlier-inserted first (scan order = col order)
__device__ __forceinline__ void insA(float v, int k, float (&V)[5], int (&K)[5]) {
#pragma unroll
    for (int t = 0; t < 5; ++t) {
        bool c = v < V[t];
        float tv = V[t]; int tk = K[t];
        V[t] = c ? v : tv; K[t] = c ? k : tk;
        v = c ? tv : v;    k = c ? tk : k;
    }
}
// ascending with index tie-break (cross-lane merges)
__device__ __forceinline__ void insAk(float v, int k, float (&V)[5], int (&K)[5]) {
#pragma unroll
    for (int t = 0; t < 5; ++t) {
        bool c = (v != V[t]) ? (v < V[t]) : ((k & 0xFFFF) < (K[t] & 0xFFFF));
        float tv = V[t]; int tk = K[t];
        V[t] = c ? v : tv; K[t] = c ? k : tk;
        v = c ? tv : v;    k = c ? tk : k;
    }
}
// descending by sim with index tie-break (matches jnp stable descending argsort)
__device__ __forceinline__ bool better(float v1, int k1, float v2, int k2) {
    if (v1 != v2) return v1 > v2;
    return (k1 & 0xFFFF) < (k2 & 0xFFFF);
}
__device__ __forceinline__ void insD(float v, int k, float (&V)[5], int (&K)[5]) {
#pragma unroll
    for (int t = 0; t < 5; ++t) {
        bool c = better(v, k, V[t], K[t]);
        float tv = V[t]; int tk = K[t];
        V[t] = c ? v : tv; K[t] = c ? k : tk;
        v = c ? tv : v;    k = c ? tk : k;
    }
}

// norms (exact f32) + class histogram + bf16 copy of X
__global__ void prep_kernel(const float* __restrict__ X, const int* __restrict__ labels,
                            float* __restrict__ norms, int* __restrict__ counts,
                            unsigned short* __restrict__ Xbf) {
    int t = blockIdx.x * 256 + threadIdx.x;       // float4 index, 131072 total
    int r = t >> 5, kq = t & 31;
    float4 v = ((const float4*)X)[t];
    float acc = v.x * v.x + v.y * v.y + v.z * v.z + v.w * v.w;
#pragma unroll
    for (int off = 1; off < 32; off <<= 1) acc += __shfl_xor(acc, off);
    if (kq == 0) norms[r] = acc;
    ushort4 hv = { f2bf(v.x), f2bf(v.y), f2bf(v.z), f2bf(v.w) };
    ((ushort4*)Xbf)[t] = hv;
    if (t < BS) atomicAdd(&counts[labels[t]], 1);
}

// 4 independent waves/block; wave = 16 rows x 256 cols (2 panels of 128).
// Swapped MFMA: A-operand = cols, B-operand = rows -> lane holds 32 cols of
// row (lane&15); lanes {l, l^16, l^32, l^48} cover the 4 col-quarters.
__global__ __launch_bounds__(256, 4) void main_kernel(
        const unsigned short* __restrict__ Xbf, const int* __restrict__ labels,
        const float* __restrict__ norms, float* __restrict__ lists) {
    __shared__ float ncS[2 * 128];
    __shared__ int   lcS[2 * 128];

    const int t = threadIdx.x;
    const int bx = blockIdx.x;
    const int slice = bx & 15;
    const int col0s = slice * SLICE_COLS;
    const int w = t >> 6, l = t & 63;
    const int rl = l & 15, q = l >> 4;
    const int row0w = (bx >> 4) * 64 + w * 16;
    const int rowG = row0w + rl;

    // stage slice norms/labels (only LDS use; 2 KB)
    if (t < 256) { ncS[t] = norms[col0s + t]; lcS[t] = labels[col0s + t]; }

    const float nR = norms[rowG];
    const int   lR = labels[rowG];

    // row fragments (B-operand): lane reads 16B of row rowG at k-chunk q*8
    s16x8 brow[4];
#pragma unroll
    for (int ks = 0; ks < 4; ++ks)
        brow[ks] = *(const s16x8*)(Xbf + (size_t)rowG * D + ks * 32 + q * 8);

    float dV[5]; int dK[5]; float sV[5]; int sK[5];   // ascending-d2' lists
#pragma unroll
    for (int i = 0; i < 5; ++i) { dV[i] = BIGD; dK[i] = 0xFFFF; sV[i] = BIGD; sK[i] = 0xFFFF; }

    __syncthreads();

#pragma unroll 1
    for (int p = 0; p < 2; ++p) {
        const int col0p = col0s + p * 128;

        f32x4 acc[8];
#pragma unroll
        for (int i = 0; i < 8; ++i) acc[i] = (f32x4){0.f, 0.f, 0.f, 0.f};

#pragma unroll
        for (int ks = 0; ks < 4; ++ks) {
            s16x8 af[8];
#pragma unroll
            for (int i = 0; i < 8; ++i)
                af[i] = *(const s16x8*)(Xbf + (size_t)(col0p + i * 16 + rl) * D + ks * 32 + q * 8);
#pragma unroll
            for (int i = 0; i < 8; ++i)
                acc[i] = __builtin_amdgcn_mfma_f32_16x16x32_bf16(af[i], brow[ks], acc[i], 0, 0, 0);
        }

        // selection directly on accumulators: lane's col = 16i + 4q + e
#pragma unroll
        for (int i = 0; i < 8; ++i) {
            f32x4 nc4 = *(const f32x4*)&ncS[p * 128 + i * 16 + q * 4];
            int4  lc4 = *(const int4*)&lcS[p * 128 + i * 16 + q * 4];
            int lcv[4] = {lc4.x, lc4.y, lc4.z, lc4.w};
#pragma unroll
            for (int e = 0; e < 4; ++e) {
                float v = fmaf(acc[i][e], -2.f, nc4[e]);   // d2' = nC - 2s (nR folded later)
                int cg = col0p + i * 16 + q * 4 + e;
                bool same = (lcv[e] == lR);
                float vd = same ? BIGD : v;
                insA(vd, cg, dV, dK);
                if (__any(same)) {
                    float vs = same ? v : BIGD;
                    insA(vs, cg, sV, sK);
                }
            }
        }
    }

    // merge the 4 col-quarters of each row (lanes l, l^16, l^32, l^48)
#pragma unroll
    for (int off = 16; off <= 32; off <<= 1) {
        float bv[5]; int bk[5];
#pragma unroll
        for (int i = 0; i < 5; ++i) { bv[i] = __shfl_xor(dV[i], off); bk[i] = __shfl_xor(dK[i], off); }
#pragma unroll
        for (int i = 0; i < 5; ++i) insAk(bv[i], bk[i], dV, dK);
#pragma unroll
        for (int i = 0; i < 5; ++i) { bv[i] = __shfl_xor(sV[i], off); bk[i] = __shfl_xor(sK[i], off); }
#pragma unroll
        for (int i = 0; i < 5; ++i) insAk(bv[i], bk[i], sV, sK);
    }

    // epilogue: one lane per row converts d2' -> sims, builds global list, writes
    if (q == 0) {
        float gV[5]; int gK[5];
#pragma unroll
        for (int i = 0; i < 5; ++i) { gV[i] = NEGV; gK[i] = 0xFFFF; }
        float sS[5];
#pragma unroll
        for (int i = 0; i < 5; ++i) {
            bool vld = dK[i] != 0xFFFF;
            float d2 = fmaxf(nR + dV[i], 0.f);
            float sim = vld ? (-sqrtf(d2) + MARGINF) : NEGV;
            insD(sim, dK[i], gV, gK);                      // diff-class: flag 0
        }
#pragma unroll
        for (int i = 0; i < 5; ++i) {
            bool vld = sK[i] != 0xFFFF;
            float d2 = fmaxf(nR + sV[i], 0.f);
            float sim = vld ? -sqrtf(d2) : NEGV;
            sS[i] = sim;
            insD(sim, sK[i] | 0x10000, gV, gK);            // same-class: flag 1
        }
        float* Lp = lists + (size_t)(rowG * NSLICE + slice) * 20;
        int* Li = (int*)Lp;
#pragma unroll
        for (int i = 0; i < 5; ++i) {
            Lp[i] = gV[i]; Li[5 + i] = gK[i];
            Lp[10 + i] = sS[i]; Li[15 + i] = sK[i];
        }
    }
}

__global__ void merge_kernel(const float* __restrict__ lists, const int* __restrict__ counts,
                             const int* __restrict__ labels, float* __restrict__ rowres) {
    int r = blockIdx.x * 256 + threadIdx.x;
    if (r >= BS) return;
    float gV[5]; int gK[5]; float sV[5]; int sK[5];
#pragma unroll
    for (int i = 0; i < 5; ++i) { gV[i] = NEGV; gK[i] = 0xFFFF; sV[i] = NEGV; sK[i] = 0xFFFF; }
    for (int s2 = 0; s2 < NSLICE; ++s2) {
        const float* Lp = lists + (size_t)(r * NSLICE + s2) * 20;
        const int* Li = (const int*)Lp;
#pragma unroll
        for (int i = 0; i < 5; ++i) insD(Lp[i], Li[5 + i], gV, gK);
#pragma unroll
        for (int i = 0; i < 5; ++i) insD(Lp[10 + i], Li[15 + i], sV, sK);
    }
    int pos = counts[labels[r]];
    int ks = (pos < 5) ? pos : 5;
    float fpsum = 0.f; int fpn = 0;
#pragma unroll
    for (int i = 0; i < 5; ++i) {
        bool isFp = (i < ks) && !((gK[i] >> 16) & 1);
        if (isFp) { fpsum += gV[i]; fpn++; }
    }
    int s0 = ks - fpn;
    float fnsum = 0.f;
#pragma unroll
    for (int i = 0; i < 5; ++i)
        if (i >= s0 && i < s0 + fpn) fnsum += sV[i];
    rowres[r] = fpsum - fnsum;
}

__global__ void reduce_kernel(const float* __restrict__ rowres, float* __restrict__ out) {
    __shared__ float sh[256];
    float acc = 0.f;
    for (int i = threadIdx.x; i < BS; i += 256) acc += rowres[i];
    sh[threadIdx.x] = acc;
    __syncthreads();
    for (int s = 128; s > 0; s >>= 1) {
        if (threadIdx.x < s) sh[threadIdx.x] += sh[threadIdx.x + s];
        __syncthreads();
    }
    if (threadIdx.x == 0) out[0] = sh[0];
}

extern "C" void kernel_launch(void* const* d_in, const int* in_sizes, int n_in,
                              void* d_out, int out_size, void* d_ws, size_t ws_size,
                              hipStream_t stream) {
    const float* X      = (const float*)d_in[0];
    const int*   labels = (const int*)d_in[1];

    float* ws     = (float*)d_ws;
    float* norms  = ws;                         // 4096 f32
    float* rowres = ws + BS;                    // 4096 f32
    int*   counts = (int*)(ws + 2 * BS);        // 512 i32
    float* lists  = ws + 2 * BS + NC;           // 4096*16*20 f32 = 5.24 MB
    unsigned short* Xbf = (unsigned short*)(ws + 2 * BS + NC + BS * NSLICE * 20); // 1 MB

    hipMemsetAsync(counts, 0, NC * sizeof(int), stream);
    prep_kernel<<<(BS * D / 4) / 256, 256, 0, stream>>>(X, labels, norms, counts, Xbf);
    main_kernel<<<64 * NSLICE, 256, 0, stream>>>(Xbf, labels, norms, lists);
    merge_kernel<<<BS / 256, 256, 0, stream>>>(lists, counts, labels, rowres);
    reduce_kernel<<<1, 256, 0, stream>>>(rowres, (float*)d_out);
}

// Round 5
// 78.700 us; speedup vs baseline: 4.4475x; 1.2791x over previous
//
#include <hip/hip_runtime.h>
#include <math.h>

#define BS 4096
#define D 128
#define NC 512
#define NS 32          // column slices
#define SC 128         // cols per slice
#define MARGINF 0.1f
#define NEGV -1e30f
#define BIGD 1e30f
#define LSTR 16        // floats per (row,slice) record: dV[5] @0, sV[5] @8

typedef float f32x4 __attribute__((ext_vector_type(4)));
typedef short s16x8 __attribute__((ext_vector_type(8)));

__device__ __forceinline__ unsigned short f2bf(float f) {
    unsigned int u = __float_as_uint(f);
    unsigned int r = u + 0x7FFFu + ((u >> 16) & 1u);
    return (unsigned short)(r >> 16);
}

// ascending sorted-insert, values only. strict < => earlier (lower col) wins ties.
__device__ __forceinline__ void insV(float v, float (&V)[5]) {
#pragma unroll
    for (int t = 0; t < 5; ++t) {
        bool c = v < V[t];
        float tv = V[t];
        V[t] = c ? v : tv;
        v = c ? tv : v;
    }
}

// descending insert with same-class flag payload (epilogue only)
__device__ __forceinline__ void insDF(float v, int f, float (&V)[5], int (&F)[5]) {
#pragma unroll
    for (int t = 0; t < 5; ++t) {
        bool c = v > V[t];
        float tv = V[t]; int tf = F[t];
        V[t] = c ? v : tv; F[t] = c ? f : tf;
        v = c ? tv : v;    f = c ? tf : f;
    }
}

// norms (exact f32) + class histogram + bf16 copy of X
__global__ void prep_kernel(const float* __restrict__ X, const int* __restrict__ labels,
                            float* __restrict__ norms, int* __restrict__ counts,
                            unsigned short* __restrict__ Xbf) {
    int t = blockIdx.x * 256 + threadIdx.x;       // float4 index, 131072 total
    int r = t >> 5, kq = t & 31;
    float4 v = ((const float4*)X)[t];
    float acc = v.x * v.x + v.y * v.y + v.z * v.z + v.w * v.w;
#pragma unroll
    for (int off = 1; off < 32; off <<= 1) acc += __shfl_xor(acc, off);
    if (kq == 0) norms[r] = acc;
    ushort4 hv = { f2bf(v.x), f2bf(v.y), f2bf(v.z), f2bf(v.w) };
    ((ushort4*)Xbf)[t] = hv;
    if (t < BS) atomicAdd(&counts[labels[t]], 1);
}

// wave = 16 rows x 128 cols (one slice). No LDS, no barriers.
// Swapped MFMA: A = cols, B = rows -> lane (rl=l&15, q=l>>4) holds cols
// {i*16 + q*4 + e} of row rl. Values-only top-5 lists in d2' = nC - 2s space.
__global__ __launch_bounds__(256, 8) void main_kernel(
        const unsigned short* __restrict__ Xbf, const int* __restrict__ labels,
        const float* __restrict__ norms, float* __restrict__ lists) {
    const int t = threadIdx.x, bx = blockIdx.x;
    const int slice = bx & (NS - 1);
    const int col0 = slice * SC;
    const int w = t >> 6, l = t & 63, rl = l & 15, q = l >> 4;
    const int rowG = (bx >> 5) * 64 + w * 16 + rl;
    const int lR = labels[rowG];

    s16x8 brow[4];
#pragma unroll
    for (int ks = 0; ks < 4; ++ks)
        brow[ks] = *(const s16x8*)(Xbf + (size_t)rowG * D + ks * 32 + q * 8);

    f32x4 acc[8];
#pragma unroll
    for (int i = 0; i < 8; ++i) acc[i] = (f32x4){0.f, 0.f, 0.f, 0.f};

#pragma unroll
    for (int ks = 0; ks < 4; ++ks) {
        s16x8 af[8];
#pragma unroll
        for (int i = 0; i < 8; ++i)
            af[i] = *(const s16x8*)(Xbf + (size_t)(col0 + i * 16 + rl) * D + ks * 32 + q * 8);
#pragma unroll
        for (int i = 0; i < 8; ++i)
            acc[i] = __builtin_amdgcn_mfma_f32_16x16x32_bf16(af[i], brow[ks], acc[i], 0, 0, 0);
    }

    float dV[5], sV[5];
#pragma unroll
    for (int i = 0; i < 5; ++i) { dV[i] = BIGD; sV[i] = BIGD; }

#pragma unroll
    for (int i = 0; i < 8; ++i) {
        f32x4 nc4 = *(const f32x4*)(norms + col0 + i * 16 + q * 4);
        int4  lc4 = *(const int4*)(labels + col0 + i * 16 + q * 4);
        int lcv[4] = {lc4.x, lc4.y, lc4.z, lc4.w};
#pragma unroll
        for (int e = 0; e < 4; ++e) {
            float v = fmaf(acc[i][e], -2.f, nc4[e]);   // d2' = nC - 2s (nR added at merge)
            bool same = (lcv[e] == lR);
            insV(same ? BIGD : v, dV);
            if (__any(same)) insV(same ? v : BIGD, sV);
        }
    }

    // merge the 4 col-quarters of each row (lanes l, l^16, l^32, l^48)
#pragma unroll
    for (int off = 16; off <= 32; off <<= 1) {
        float bv[5];
#pragma unroll
        for (int i = 0; i < 5; ++i) bv[i] = __shfl_xor(dV[i], off);
#pragma unroll
        for (int i = 0; i < 5; ++i) insV(bv[i], dV);
#pragma unroll
        for (int i = 0; i < 5; ++i) bv[i] = __shfl_xor(sV[i], off);
#pragma unroll
        for (int i = 0; i < 5; ++i) insV(bv[i], sV);
    }

    if (q == 0) {
        float* Lp = lists + ((size_t)rowG * NS + slice) * LSTR;
        *(f32x4*)Lp = (f32x4){dV[0], dV[1], dV[2], dV[3]};
        Lp[4] = dV[4];
        *(f32x4*)(Lp + 8) = (f32x4){sV[0], sV[1], sV[2], sV[3]};
        Lp[12] = sV[4];
    }
}

// 2 threads per row: even merges diff lists, odd merges same lists (uniform code).
// Even thread combines via shfl and computes the row loss; block-partial summed.
__global__ __launch_bounds__(256) void merge_kernel(
        const float* __restrict__ lists, const int* __restrict__ counts,
        const int* __restrict__ labels, const float* __restrict__ norms,
        float* __restrict__ partials) {
    __shared__ float sh[256];
    const int t = threadIdx.x, bx = blockIdx.x;
    const int gid = bx * 256 + t;
    const int r = gid >> 1, half = gid & 1;

    const float* base = lists + (size_t)r * NS * LSTR + half * 8;
    float V[5];
#pragma unroll
    for (int i = 0; i < 5; ++i) V[i] = BIGD;
#pragma unroll 4
    for (int s = 0; s < NS; ++s) {
        f32x4 v4 = *(const f32x4*)(base + s * LSTR);
        float v5 = base[s * LSTR + 4];
        insV(v4.x, V); insV(v4.y, V); insV(v4.z, V); insV(v4.w, V); insV(v5, V);
    }

    float oV[5];
#pragma unroll
    for (int i = 0; i < 5; ++i) oV[i] = __shfl_xor(V[i], 1);

    float res = 0.f;
    if (half == 0) {
        const float nR = norms[r];
        const int pos = counts[labels[r]];
        const int ks = (pos < 5) ? pos : 5;
        float dS[5], sS[5];
#pragma unroll
        for (int i = 0; i < 5; ++i) {
            float dv = V[i];  bool ok = dv < 1e29f;
            dS[i] = ok ? (-sqrtf(fmaxf(nR + dv, 0.f)) + MARGINF) : NEGV;
        }
#pragma unroll
        for (int i = 0; i < 5; ++i) {
            float sv = oV[i]; bool ok = sv < 1e29f;
            sS[i] = ok ? -sqrtf(fmaxf(nR + sv, 0.f)) : NEGV;
        }
        float mV[5]; int mF[5];
#pragma unroll
        for (int i = 0; i < 5; ++i) { mV[i] = dS[i]; mF[i] = 0; }
#pragma unroll
        for (int i = 0; i < 5; ++i) insDF(sS[i], 1, mV, mF);

        float fpsum = 0.f; int fpn = 0;
#pragma unroll
        for (int i = 0; i < 5; ++i)
            if (i < ks && mF[i] == 0) { fpsum += mV[i]; fpn++; }
        const int s0 = ks - fpn;
        float fnsum = 0.f;
#pragma unroll
        for (int i = 0; i < 5; ++i)
            if (i >= s0 && i < s0 + fpn) fnsum += sS[i];
        res = fpsum - fnsum;
    }
    sh[t] = res;
    __syncthreads();
    for (int s = 128; s > 0; s >>= 1) {
        if (t < s) sh[t] += sh[t + s];
        __syncthreads();
    }
    if (t == 0) partials[bx] = sh[0];
}

__global__ void reduce_kernel(const float* __restrict__ partials, float* __restrict__ out) {
    const int l = threadIdx.x;
    float v = (l < 32) ? partials[l] : 0.f;
#pragma unroll
    for (int off = 1; off < 64; off <<= 1) v += __shfl_xor(v, off);
    if (l == 0) out[0] = v;
}

extern "C" void kernel_launch(void* const* d_in, const int* in_sizes, int n_in,
                              void* d_out, int out_size, void* d_ws, size_t ws_size,
                              hipStream_t stream) {
    const float* X      = (const float*)d_in[0];
    const int*   labels = (const int*)d_in[1];

    float* ws       = (float*)d_ws;
    float* norms    = ws;                        // 4096 f32
    float* partials = ws + BS;                   // 32 f32 (padded to 64)
    int*   counts   = (int*)(ws + BS + 64);      // 512 i32
    float* lists    = ws + BS + 64 + NC;         // 4096*32*16 f32 = 8.39 MB
    unsigned short* Xbf = (unsigned short*)(lists + (size_t)BS * NS * LSTR); // 1 MB

    hipMemsetAsync(counts, 0, NC * sizeof(int), stream);
    prep_kernel<<<(BS * D / 4) / 256, 256, 0, stream>>>(X, labels, norms, counts, Xbf);
    main_kernel<<<(BS / 64) * NS, 256, 0, stream>>>(Xbf, labels, norms, lists);
    merge_kernel<<<(BS * 2) / 256, 256, 0, stream>>>(lists, counts, labels, norms, partials);
    reduce_kernel<<<1, 64, 0, stream>>>(partials, (float*)d_out);
}

// Round 6
// 52.357 us; speedup vs baseline: 6.6851x; 1.5031x over previous
//
#include <hip/hip_runtime.h>
#include <math.h>

#define BS 4096
#define D 128
#define NC 512
#define NS 32          // column slices
#define SC 128         // cols per slice
#define MARGINF 0.1f
#define NEGV -1e30f
#define BIGD 1e30f
#define LSTR 16        // floats per (row,slice) record: dV[5] @0, sV[5] @8

typedef float f32x4 __attribute__((ext_vector_type(4)));
typedef short s16x8 __attribute__((ext_vector_type(8)));

__device__ __forceinline__ unsigned short f2bf(float f) {
    unsigned int u = __float_as_uint(f);
    unsigned int r = u + 0x7FFFu + ((u >> 16) & 1u);
    return (unsigned short)(r >> 16);
}

// ascending sorted-insert, values only. strict < => earlier (lower col) wins ties.
__device__ __forceinline__ void insV(float v, float (&V)[5]) {
#pragma unroll
    for (int t = 0; t < 5; ++t) {
        bool c = v < V[t];
        float tv = V[t];
        V[t] = c ? v : tv;
        v = c ? tv : v;
    }
}

// descending insert with same-class flag payload (epilogue only)
__device__ __forceinline__ void insDF(float v, int f, float (&V)[5], int (&F)[5]) {
#pragma unroll
    for (int t = 0; t < 5; ++t) {
        bool c = v > V[t];
        float tv = V[t]; int tf = F[t];
        V[t] = c ? v : tv; F[t] = c ? f : tf;
        v = c ? tv : v;    f = c ? tf : f;
    }
}

// norms (exact f32) + class histogram + fragment-tiled bf16 copy of X.
// Layout Xp: for row group g=row>>4, k-chunk ks (32 elems), lane l=(q*16+rl):
//   byte offset = g*4096 + ks*1024 + l*16  holds row (16g+rl), k [ks*32+q*8, +8)
// => every MFMA fragment load in main is one contiguous 1KB wave-load.
__global__ void prep_kernel(const float* __restrict__ X, const int* __restrict__ labels,
                            float* __restrict__ norms, int* __restrict__ counts,
                            unsigned short* __restrict__ Xp) {
    int t = blockIdx.x * 256 + threadIdx.x;       // float4 index, 131072 total
    int r = t >> 5, kq = t & 31;
    float4 v = ((const float4*)X)[t];
    float acc = v.x * v.x + v.y * v.y + v.z * v.z + v.w * v.w;
#pragma unroll
    for (int off = 1; off < 32; off <<= 1) acc += __shfl_xor(acc, off);
    if (kq == 0) norms[r] = acc;
    ushort4 hv = { f2bf(v.x), f2bf(v.y), f2bf(v.z), f2bf(v.w) };
    int g = r >> 4, rl = r & 15;
    int ks = kq >> 3, q = (kq >> 1) & 3, half = kq & 1;
    *(ushort4*)((char*)Xp + g * 4096 + ks * 1024 + (q * 16 + rl) * 16 + half * 8) = hv;
    if (t < BS) atomicAdd(&counts[labels[t]], 1);
}

// wave = 16 rows x 128 cols (one slice). No LDS, no barriers, coalesced loads.
// Swapped MFMA: A = cols, B = rows -> lane (rl=l&15, q=l>>4) holds cols
// {i*16 + q*4 + e} of row rl. Values-only top-5 lists in d2' = nC - 2s space.
__global__ __launch_bounds__(256, 8) void main_kernel(
        const unsigned short* __restrict__ Xp, const int* __restrict__ labels,
        const float* __restrict__ norms, float* __restrict__ lists) {
    const int t = threadIdx.x, bx = blockIdx.x;
    const int slice = bx & (NS - 1);
    const int col0 = slice * SC;
    const int w = t >> 6, l = t & 63, rl = l & 15, q = l >> 4;
    const int gRow = (bx >> 5) * 4 + w;            // this wave's 16-row group
    const int rowG = gRow * 16 + rl;
    const int lR = labels[rowG];
    const char* Pb = (const char*)Xp;

    s16x8 brow[4];
#pragma unroll
    for (int ks = 0; ks < 4; ++ks)
        brow[ks] = *(const s16x8*)(Pb + (size_t)gRow * 4096 + ks * 1024 + l * 16);

    f32x4 acc[8];
#pragma unroll
    for (int i = 0; i < 8; ++i) acc[i] = (f32x4){0.f, 0.f, 0.f, 0.f};

#pragma unroll
    for (int ks = 0; ks < 4; ++ks) {
        s16x8 af[8];
#pragma unroll
        for (int i = 0; i < 8; ++i)
            af[i] = *(const s16x8*)(Pb + (size_t)(slice * 8 + i) * 4096 + ks * 1024 + l * 16);
#pragma unroll
        for (int i = 0; i < 8; ++i)
            acc[i] = __builtin_amdgcn_mfma_f32_16x16x32_bf16(af[i], brow[ks], acc[i], 0, 0, 0);
    }

    float dV[5], sV[5];
#pragma unroll
    for (int i = 0; i < 5; ++i) { dV[i] = BIGD; sV[i] = BIGD; }

#pragma unroll
    for (int i = 0; i < 8; ++i) {
        f32x4 nc4 = *(const f32x4*)(norms + col0 + i * 16 + q * 4);
        int4  lc4 = *(const int4*)(labels + col0 + i * 16 + q * 4);
        int lcv[4] = {lc4.x, lc4.y, lc4.z, lc4.w};
#pragma unroll
        for (int e = 0; e < 4; ++e) {
            float v = fmaf(acc[i][e], -2.f, nc4[e]);   // d2' = nC - 2s (nR added at merge)
            bool same = (lcv[e] == lR);
            insV(same ? BIGD : v, dV);
            if (__any(same)) insV(same ? v : BIGD, sV);
        }
    }

    // merge the 4 col-quarters of each row (lanes l, l^16, l^32, l^48)
#pragma unroll
    for (int off = 16; off <= 32; off <<= 1) {
        float bv[5];
#pragma unroll
        for (int i = 0; i < 5; ++i) bv[i] = __shfl_xor(dV[i], off);
#pragma unroll
        for (int i = 0; i < 5; ++i) insV(bv[i], dV);
#pragma unroll
        for (int i = 0; i < 5; ++i) bv[i] = __shfl_xor(sV[i], off);
#pragma unroll
        for (int i = 0; i < 5; ++i) insV(bv[i], sV);
    }

    if (q == 0) {
        float* Lp = lists + ((size_t)rowG * NS + slice) * LSTR;
        *(f32x4*)Lp = (f32x4){dV[0], dV[1], dV[2], dV[3]};
        Lp[4] = dV[4];
        *(f32x4*)(Lp + 8) = (f32x4){sV[0], sV[1], sV[2], sV[3]};
        Lp[12] = sV[4];
    }
}

// 2 threads per row: even merges diff lists, odd merges same lists (uniform code).
// Even thread combines via shfl and computes the row loss; block-partial summed.
__global__ __launch_bounds__(256) void merge_kernel(
        const float* __restrict__ lists, const int* __restrict__ counts,
        const int* __restrict__ labels, const float* __restrict__ norms,
        float* __restrict__ partials) {
    __shared__ float sh[256];
    const int t = threadIdx.x, bx = blockIdx.x;
    const int gid = bx * 256 + t;
    const int r = gid >> 1, half = gid & 1;

    const float* base = lists + (size_t)r * NS * LSTR + half * 8;
    float V[5];
#pragma unroll
    for (int i = 0; i < 5; ++i) V[i] = BIGD;
#pragma unroll 4
    for (int s = 0; s < NS; ++s) {
        f32x4 v4 = *(const f32x4*)(base + s * LSTR);
        float v5 = base[s * LSTR + 4];
        insV(v4.x, V); insV(v4.y, V); insV(v4.z, V); insV(v4.w, V); insV(v5, V);
    }

    float oV[5];
#pragma unroll
    for (int i = 0; i < 5; ++i) oV[i] = __shfl_xor(V[i], 1);

    float res = 0.f;
    if (half == 0) {
        const float nR = norms[r];
        const int pos = counts[labels[r]];
        const int ks = (pos < 5) ? pos : 5;
        float dS[5], sS[5];
#pragma unroll
        for (int i = 0; i < 5; ++i) {
            float dv = V[i];  bool ok = dv < 1e29f;
            dS[i] = ok ? (-sqrtf(fmaxf(nR + dv, 0.f)) + MARGINF) : NEGV;
        }
#pragma unroll
        for (int i = 0; i < 5; ++i) {
            float sv = oV[i]; bool ok = sv < 1e29f;
            sS[i] = ok ? -sqrtf(fmaxf(nR + sv, 0.f)) : NEGV;
        }
        float mV[5]; int mF[5];
#pragma unroll
        for (int i = 0; i < 5; ++i) { mV[i] = dS[i]; mF[i] = 0; }
#pragma unroll
        for (int i = 0; i < 5; ++i) insDF(sS[i], 1, mV, mF);

        float fpsum = 0.f; int fpn = 0;
#pragma unroll
        for (int i = 0; i < 5; ++i)
            if (i < ks && mF[i] == 0) { fpsum += mV[i]; fpn++; }
        const int s0 = ks - fpn;
        float fnsum = 0.f;
#pragma unroll
        for (int i = 0; i < 5; ++i)
            if (i >= s0 && i < s0 + fpn) fnsum += sS[i];
        res = fpsum - fnsum;
    }
    sh[t] = res;
    __syncthreads();
    for (int s = 128; s > 0; s >>= 1) {
        if (t < s) sh[t] += sh[t + s];
        __syncthreads();
    }
    if (t == 0) partials[bx] = sh[0];
}

__global__ void reduce_kernel(const float* __restrict__ partials, float* __restrict__ out) {
    const int l = threadIdx.x;
    float v = (l < 32) ? partials[l] : 0.f;
#pragma unroll
    for (int off = 1; off < 64; off <<= 1) v += __shfl_xor(v, off);
    if (l == 0) out[0] = v;
}

extern "C" void kernel_launch(void* const* d_in, const int* in_sizes, int n_in,
                              void* d_out, int out_size, void* d_ws, size_t ws_size,
                              hipStream_t stream) {
    const float* X      = (const float*)d_in[0];
    const int*   labels = (const int*)d_in[1];

    float* ws       = (float*)d_ws;
    float* norms    = ws;                        // 4096 f32
    float* partials = ws + BS;                   // 32 f32 (padded to 64)
    int*   counts   = (int*)(ws + BS + 64);      // 512 i32
    float* lists    = ws + BS + 64 + NC;         // 4096*32*16 f32 = 8.39 MB
    unsigned short* Xp = (unsigned short*)(lists + (size_t)BS * NS * LSTR); // 1 MB

    hipMemsetAsync(counts, 0, NC * sizeof(int), stream);
    prep_kernel<<<(BS * D / 4) / 256, 256, 0, stream>>>(X, labels, norms, counts, Xp);
    main_kernel<<<(BS / 64) * NS, 256, 0, stream>>>(Xp, labels, norms, lists);
    merge_kernel<<<(BS * 2) / 256, 256, 0, stream>>>(lists, counts, labels, norms, partials);
    reduce_kernel<<<1, 64, 0, stream>>>(partials, (float*)d_out);
}

// Round 7
// 44.996 us; speedup vs baseline: 7.7788x; 1.1636x over previous
//
#include <hip/hip_runtime.h>
#include <math.h>

#define BS 4096
#define D 128
#define NC 512
#define NS 32          // column slices
#define SC 128         // cols per slice
#define MARGINF 0.1f
#define NEGV -1e30f
#define BIGD 1e30f
#define LSTR 12        // floats per (row,slice) record: dV[0..3]@0, {dV4,sV4,pad,pad}@4, sV[0..3]@8

typedef float f32x4 __attribute__((ext_vector_type(4)));
typedef short s16x8 __attribute__((ext_vector_type(8)));

__device__ __forceinline__ unsigned short f2bf(float f) {
    unsigned int u = __float_as_uint(f);
    unsigned int r = u + 0x7FFFu + ((u >> 16) & 1u);
    return (unsigned short)(r >> 16);
}

// sorted-ascending top-5 insert via med3: W[0]=min(V0,v), W[t]=med3(V[t-1],V[t],v).
// 5 INDEPENDENT ops (v_min + 4x v_med3) -- no serial chain within the insert.
__device__ __forceinline__ void insV(float v, float (&V)[5]) {
    float w0 = fminf(V[0], v);
    float w1 = __builtin_amdgcn_fmed3f(V[0], V[1], v);
    float w2 = __builtin_amdgcn_fmed3f(V[1], V[2], v);
    float w3 = __builtin_amdgcn_fmed3f(V[2], V[3], v);
    float w4 = __builtin_amdgcn_fmed3f(V[3], V[4], v);
    V[0] = w0; V[1] = w1; V[2] = w2; V[3] = w3; V[4] = w4;
}

// descending insert with same-class flag payload (epilogue only, 5 uses/row)
__device__ __forceinline__ void insDF(float v, int f, float (&V)[5], int (&F)[5]) {
#pragma unroll
    for (int t = 0; t < 5; ++t) {
        bool c = v > V[t];
        float tv = V[t]; int tf = F[t];
        V[t] = c ? v : tv; F[t] = c ? f : tf;
        v = c ? tv : v;    f = c ? tf : f;
    }
}

// norms + class histogram + fragment-tiled bf16 copy of X (LDS-staged transpose,
// both global sides coalesced; LDS XOR-swizzled 16B chunks => <=2-way banks).
// Xp layout: row group g=row>>4, k-chunk ks, lane l2=(q*16+rl):
//   byte off = g*4096 + ks*1024 + l2*16 holds row (16g+rl), k [ks*32+q*8, +8)
__global__ __launch_bounds__(256) void prep_kernel(
        const float* __restrict__ X, const int* __restrict__ labels,
        float* __restrict__ norms, int* __restrict__ counts,
        unsigned short* __restrict__ Xp) {
    __shared__ __align__(16) unsigned short sb[32 * 128];   // 8 KB
    const int t = threadIdx.x, bx = blockIdx.x;
    const int row0 = bx * 32;

#pragma unroll
    for (int i = 0; i < 4; ++i) {
        int idx = i * 256 + t;                 // float4 units 0..1023
        int lr = idx >> 5, kq = idx & 31;
        float4 v = ((const float4*)X)[(size_t)row0 * 32 + idx];
        float acc = v.x * v.x + v.y * v.y + v.z * v.z + v.w * v.w;
#pragma unroll
        for (int off = 1; off < 32; off <<= 1) acc += __shfl_xor(acc, off);
        if (kq == 0) norms[row0 + lr] = acc;
        ushort4 hv = { f2bf(v.x), f2bf(v.y), f2bf(v.z), f2bf(v.w) };
        int chunk = (kq >> 1) ^ (lr & 7);
        *(ushort4*)((char*)sb + lr * 256 + (chunk << 4) + (kq & 1) * 8) = hv;
    }
    if (t < 32) atomicAdd(&counts[labels[row0 + t]], 1);
    __syncthreads();

#pragma unroll
    for (int i = 0; i < 2; ++i) {
        int u = i * 256 + t;                   // 16B units 0..511
        int j = u >> 8, ug = u & 255;
        int ks = ug >> 6, l2 = ug & 63;
        int lr = j * 16 + (l2 & 15), q = l2 >> 4;
        int chunk = (ks * 4 + q) ^ (lr & 7);
        ulonglong2 d = *(const ulonglong2*)((const char*)sb + lr * 256 + (chunk << 4));
        *(ulonglong2*)((char*)Xp + (size_t)(bx * 2 + j) * 4096 + ks * 1024 + l2 * 16) = d;
    }
}

// wave = 16 rows x 128 cols (one slice). No LDS, coalesced 1KB fragment loads.
// Swapped MFMA: lane (rl=l&15, q=l>>4) holds cols {i*16+q*4+e} of row rl.
__global__ __launch_bounds__(256, 8) void main_kernel(
        const unsigned short* __restrict__ Xp, const int* __restrict__ labels,
        const float* __restrict__ norms, float* __restrict__ lists) {
    const int t = threadIdx.x, bx = blockIdx.x;
    const int slice = bx & (NS - 1);
    const int col0 = slice * SC;
    const int w = t >> 6, l = t & 63, rl = l & 15, q = l >> 4;
    const int gRow = (bx >> 5) * 4 + w;
    const int rowG = gRow * 16 + rl;
    const int lR = labels[rowG];
    const char* Pb = (const char*)Xp;

    s16x8 brow[4];
#pragma unroll
    for (int ks = 0; ks < 4; ++ks)
        brow[ks] = *(const s16x8*)(Pb + (size_t)gRow * 4096 + ks * 1024 + l * 16);

    f32x4 acc[8];
#pragma unroll
    for (int i = 0; i < 8; ++i) acc[i] = (f32x4){0.f, 0.f, 0.f, 0.f};

#pragma unroll
    for (int ks = 0; ks < 4; ++ks) {
        s16x8 af[8];
#pragma unroll
        for (int i = 0; i < 8; ++i)
            af[i] = *(const s16x8*)(Pb + (size_t)(slice * 8 + i) * 4096 + ks * 1024 + l * 16);
#pragma unroll
        for (int i = 0; i < 8; ++i)
            acc[i] = __builtin_amdgcn_mfma_f32_16x16x32_bf16(af[i], brow[ks], acc[i], 0, 0, 0);
    }

    float dV[5], sV[5];
#pragma unroll
    for (int i = 0; i < 5; ++i) { dV[i] = BIGD; sV[i] = BIGD; }

#pragma unroll
    for (int i = 0; i < 8; ++i) {
        f32x4 nc4 = *(const f32x4*)(norms + col0 + i * 16 + q * 4);
        int4  lc4 = *(const int4*)(labels + col0 + i * 16 + q * 4);
        int lcv[4] = {lc4.x, lc4.y, lc4.z, lc4.w};
#pragma unroll
        for (int e = 0; e < 4; ++e) {
            float v = fmaf(acc[i][e], -2.f, nc4[e]);   // d2' = nC - 2s (nR added at merge)
            bool same = (lcv[e] == lR);
            insV(same ? BIGD : v, dV);
            if (__any(same)) insV(same ? v : BIGD, sV);
        }
    }

    // merge the 4 col-quarters of each row (lanes l, l^16, l^32, l^48)
#pragma unroll
    for (int off = 16; off <= 32; off <<= 1) {
        float bv[5];
#pragma unroll
        for (int i = 0; i < 5; ++i) bv[i] = __shfl_xor(dV[i], off);
#pragma unroll
        for (int i = 0; i < 5; ++i) insV(bv[i], dV);
#pragma unroll
        for (int i = 0; i < 5; ++i) bv[i] = __shfl_xor(sV[i], off);
#pragma unroll
        for (int i = 0; i < 5; ++i) insV(bv[i], sV);
    }

    if (q == 0) {
        float* Lp = lists + ((size_t)rowG * NS + slice) * LSTR;
        *(f32x4*)Lp       = (f32x4){dV[0], dV[1], dV[2], dV[3]};
        *(f32x4*)(Lp + 4) = (f32x4){dV[4], sV[4], 0.f, 0.f};
        *(f32x4*)(Lp + 8) = (f32x4){sV[0], sV[1], sV[2], sV[3]};
    }
}

// 8 threads per row: part&1 = {diff,same} half, part>>1 = slice-octant.
// shfl-merge octants (xor 2,4), then epilogue on part==0 with partner xor 1.
__global__ __launch_bounds__(256) void merge_kernel(
        const float* __restrict__ lists, const int* __restrict__ counts,
        const int* __restrict__ labels, const float* __restrict__ norms,
        float* __restrict__ partials) {
    __shared__ float sh[256];
    const int t = threadIdx.x, bx = blockIdx.x;
    const int gid = bx * 256 + t;
    const int r = gid >> 3, part = gid & 7;
    const int half = part & 1, s8 = part >> 1;

    float V[5];
#pragma unroll
    for (int i = 0; i < 5; ++i) V[i] = BIGD;
#pragma unroll
    for (int s = 0; s < 8; ++s) {
        const float* rec = lists + (size_t)(r * NS + s8 * 8 + s) * LSTR + half * 8;
        f32x4 v4 = *(const f32x4*)rec;
        float v5 = rec[half ? -3 : 4];         // dV4 at +4; sV4 at record+5 (= rec-3)
        insV(v4.x, V); insV(v4.y, V); insV(v4.z, V); insV(v4.w, V); insV(v5, V);
    }
#pragma unroll
    for (int off = 2; off <= 4; off <<= 1) {
        float bv[5];
#pragma unroll
        for (int i = 0; i < 5; ++i) bv[i] = __shfl_xor(V[i], off);
#pragma unroll
        for (int i = 0; i < 5; ++i) insV(bv[i], V);
    }
    float oV[5];
#pragma unroll
    for (int i = 0; i < 5; ++i) oV[i] = __shfl_xor(V[i], 1);

    float res = 0.f;
    if (part == 0) {
        const float nR = norms[r];
        const int pos = counts[labels[r]];
        const int ks = (pos < 5) ? pos : 5;
        float dS[5], sS[5];
#pragma unroll
        for (int i = 0; i < 5; ++i) {
            float dv = V[i];  bool ok = dv < 1e29f;
            dS[i] = ok ? (-sqrtf(fmaxf(nR + dv, 0.f)) + MARGINF) : NEGV;
        }
#pragma unroll
        for (int i = 0; i < 5; ++i) {
            float sv = oV[i]; bool ok = sv < 1e29f;
            sS[i] = ok ? -sqrtf(fmaxf(nR + sv, 0.f)) : NEGV;
        }
        float mV[5]; int mF[5];
#pragma unroll
        for (int i = 0; i < 5; ++i) { mV[i] = dS[i]; mF[i] = 0; }
#pragma unroll
        for (int i = 0; i < 5; ++i) insDF(sS[i], 1, mV, mF);

        float fpsum = 0.f; int fpn = 0;
#pragma unroll
        for (int i = 0; i < 5; ++i)
            if (i < ks && mF[i] == 0) { fpsum += mV[i]; fpn++; }
        const int s0 = ks - fpn;
        float fnsum = 0.f;
#pragma unroll
        for (int i = 0; i < 5; ++i)
            if (i >= s0 && i < s0 + fpn) fnsum += sS[i];
        res = fpsum - fnsum;
    }
    sh[t] = res;
    __syncthreads();
    for (int s = 128; s > 0; s >>= 1) {
        if (t < s) sh[t] += sh[t + s];
        __syncthreads();
    }
    if (t == 0) partials[bx] = sh[0];
}

__global__ void reduce_kernel(const float* __restrict__ partials, float* __restrict__ out) {
    const int l = threadIdx.x;
    float v = partials[l] + partials[l + 64];
#pragma unroll
    for (int off = 1; off < 64; off <<= 1) v += __shfl_xor(v, off);
    if (l == 0) out[0] = v;
}

extern "C" void kernel_launch(void* const* d_in, const int* in_sizes, int n_in,
                              void* d_out, int out_size, void* d_ws, size_t ws_size,
                              hipStream_t stream) {
    const float* X      = (const float*)d_in[0];
    const int*   labels = (const int*)d_in[1];

    float* ws       = (float*)d_ws;
    float* norms    = ws;                        // 4096 f32
    float* partials = ws + BS;                   // 128 f32
    int*   counts   = (int*)(ws + BS + 128);     // 512 i32
    float* lists    = ws + BS + 128 + NC;        // 4096*32*12 f32 = 6.29 MB
    unsigned short* Xp = (unsigned short*)(lists + (size_t)BS * NS * LSTR); // 1 MB

    hipMemsetAsync(counts, 0, NC * sizeof(int), stream);
    prep_kernel<<<BS / 32, 256, 0, stream>>>(X, labels, norms, counts, Xp);
    main_kernel<<<(BS / 64) * NS, 256, 0, stream>>>(Xp, labels, norms, lists);
    merge_kernel<<<(BS * 8) / 256, 256, 0, stream>>>(lists, counts, labels, norms, partials);
    reduce_kernel<<<1, 64, 0, stream>>>(partials, (float*)d_out);
}